// Round 8
// baseline (245.119 us; speedup 1.0000x reference)
//
#include <hip/hip_runtime.h>
#include <math.h>

#define N_NODES 50000
#define N_EDGES 1600000
#define IN_DIM  128
#define HC      64   // H*C
#define NH      4    // heads
#define SLOTS   72   // padded CSR slots per node; true max degree ~55
#define NB      1564 // buckets: dst >> 5, 32 nodes each (1564*32 = 50048)
#define BCAP    1280 // per-bucket capacity: mean 1024 + 8 sigma

// ---------------------------------------------------------------- GEMM + logits
// W-in-VGPR gemm: lane l owns W column l (128 floats = 32 float4 VGPRs).
// Wave computes 16 full 64-col output rows; x row read via 32 same-address
// float4 loads (one request/wave; x streamed exactly once, 25.6 MB). Zero LDS.
// 4 independent acc chains per node; VALU-bound ~5-10 us predicted.
__global__ __launch_bounds__(256) void gemm_attn_kernel(
    const float* __restrict__ x, const float* __restrict__ W,
    const float* __restrict__ att_src, const float* __restrict__ att_dst,
    float* __restrict__ xp, float* __restrict__ a_src, float* __restrict__ a_dst) {
    int tid = (int)threadIdx.x;
    int l   = tid & 63;
    int wave = blockIdx.x * 4 + (tid >> 6);   // 782*4 = 3128 waves
    int h = l >> 4;

    float4 wv[32];
    const float4* wp = (const float4*)(W + (size_t)l * IN_DIM);  // W[l][0..127]
#pragma unroll
    for (int c = 0; c < 32; ++c) wv[c] = wp[c];
    float as = att_src[l], ad = att_dst[l];

    int nbase = wave * 16;                    // 3128*16 = 50048 >= 50000
    for (int r = 0; r < 16; ++r) {
        int n = nbase + r;
        if (n >= N_NODES) break;              // wave-uniform branch
        const float4* xr = (const float4*)(x + (size_t)n * IN_DIM);
        float a0 = 0.f, a1 = 0.f, a2 = 0.f, a3 = 0.f;
#pragma unroll
        for (int c = 0; c < 32; ++c) {
            float4 xv = xr[c];                // same addr across lanes: 1 req/wave
            a0 = fmaf(xv.x, wv[c].x, a0);
            a1 = fmaf(xv.y, wv[c].y, a1);
            a2 = fmaf(xv.z, wv[c].z, a2);
            a3 = fmaf(xv.w, wv[c].w, a3);
        }
        float acc = (a0 + a1) + (a2 + a3);
        xp[(size_t)n * HC + l] = acc;         // coalesced 256B row store
        float ps = acc * as;
        float pd = acc * ad;
#pragma unroll
        for (int off = 1; off < 16; off <<= 1) {
            ps += __shfl_xor(ps, off, 64);
            pd += __shfl_xor(pd, off, 64);
        }
        if ((l & 15) == 0) {
            a_src[n * NH + h] = ps;
            a_dst[n * NH + h] = pd;
        }
    }
}

// ---------------------------------------------------------------- bucket pass
// Bin edges by dst>>5 (32-node buckets). LDS-atomic local positions + one
// global atomic per non-empty bucket per block; dense packed appends.
// Record: src (20 bits) | (dst & 31) << 20.
__global__ __launch_bounds__(256) void bucket_kernel(
    const int* __restrict__ ei, int* __restrict__ gcursor,
    unsigned int* __restrict__ barr) {
    __shared__ int lcount[NB];
    __shared__ int lbase[NB];
    int tid = threadIdx.x;
    for (int j = tid; j < NB; j += 256) lcount[j] = 0;
    __syncthreads();
    int gid = blockIdx.x * 256 + tid;            // 16-edge group id (100000 total)
    bool active = gid < N_EDGES / 16;            // NO early return (barriers)
    int s[16], d[16], b[16], lpos[16];
    if (active) {
        const int4* sp = (const int4*)ei;
        const int4* dp = (const int4*)(ei + N_EDGES);
#pragma unroll
        for (int v = 0; v < 4; ++v) {
            int4 sv = sp[4 * gid + v];
            int4 dv = dp[4 * gid + v];
            s[4*v+0] = sv.x; s[4*v+1] = sv.y; s[4*v+2] = sv.z; s[4*v+3] = sv.w;
            d[4*v+0] = dv.x; d[4*v+1] = dv.y; d[4*v+2] = dv.z; d[4*v+3] = dv.w;
        }
#pragma unroll
        for (int u = 0; u < 16; ++u) {
            b[u] = d[u] >> 5;
            lpos[u] = atomicAdd(&lcount[b[u]], 1);
        }
    }
    __syncthreads();
    for (int j = tid; j < NB; j += 256) {
        int c = lcount[j];
        lbase[j] = (c > 0) ? atomicAdd(&gcursor[j], c) : 0;
    }
    __syncthreads();
    if (active) {
#pragma unroll
        for (int u = 0; u < 16; ++u) {
            int pos = lbase[b[u]] + lpos[u];
            if (pos < BCAP)   // statistically impossible overflow; never corrupt
                barr[(size_t)b[u] * BCAP + pos] =
                    (unsigned)s[u] | ((unsigned)(d[u] & 31) << 20);
        }
    }
}

// ---------------------------------------------------------------- fused CSR + gather
// One 256-thread block per 32-node bucket (NB=1564 -> 6.1 blocks/CU, ~2x the
// occupancy of R7's 64-node version; phase A halves). Phase A: coalesced
// uint4 record reads -> LDS CSR (LDS atomics only). Phase B: 4 dst/wave,
// 16 lanes/dst, float4/lane; 2 rounds cover 32 nodes.
__global__ __launch_bounds__(256) void fused_gather_kernel(
    const unsigned int* __restrict__ barr, const int* __restrict__ gcursor,
    const float* __restrict__ a_src, const float* __restrict__ a_dst,
    const float* __restrict__ xp, const float* __restrict__ bias,
    float* __restrict__ out) {
    __shared__ int lcsr[32 * SLOTS];   // 9216 B
    __shared__ int deg[32];
    int b = blockIdx.x, tid = (int)threadIdx.x;
    if (tid < 32) deg[tid] = 0;
    __syncthreads();
    int n = gcursor[b];
    n = (n < BCAP) ? n : BCAP;
    const unsigned int* src = barr + (size_t)b * BCAP;

    // ---- phase A: build LDS adjacency (1280 records max = 2 rounds)
    for (int i0 = 0; i0 < n; i0 += 1024) {
        int ibase = i0 + tid * 4;
        unsigned v[4]; bool val[4]; int dp[4], pos[4];
        if (ibase < n) {
            uint4 r = *(const uint4*)(src + ibase);   // BCAP mult of 4, 16B aligned
            v[0] = r.x; v[1] = r.y; v[2] = r.z; v[3] = r.w;
        } else { v[0] = v[1] = v[2] = v[3] = 0u; }
#pragma unroll
        for (int u = 0; u < 4; ++u) {
            val[u] = (ibase + u) < n;
            dp[u] = (int)(v[u] >> 20);
            if (val[u]) pos[u] = atomicAdd(&deg[dp[u]], 1);
        }
#pragma unroll
        for (int u = 0; u < 4; ++u)
            if (val[u] && pos[u] < SLOTS)
                lcsr[dp[u] * SLOTS + pos[u]] = (int)(v[u] & 0xFFFFF);
    }
    __syncthreads();

    // ---- phase B: gather
    int l = tid & 63;
    int w = tid >> 6;                 // wave 0..3
    int q = l >> 4;                   // quarter
    int i = l & 15;                   // lane within quarter
    int h = i >> 2;                   // head of this lane's 4 channels
    const float* xpi = xp + 4 * i;
    const float* asrch = a_src + h;
    int qsel = l & 48;
    float4 bz = *(const float4*)(bias + 4 * i);

#pragma unroll
    for (int r = 0; r < 2; ++r) {
        int dl = w * 8 + r * 4 + q;           // local node 0..31
        int dst = (b << 5) + dl;
        int dg = deg[dl];
        dg = (dg < SLOTS) ? dg : SLOTS;
        // dst in [50000,50048): a_dst read lands in d_ws gap region (safe,
        // allocated); dg==0 there and the store is guarded.
        float adh = a_dst[dst * NH + h];
        int sreg[5];
        sreg[0] = lcsr[dl * SLOTS + i];
        sreg[1] = lcsr[dl * SLOTS + 16 + i];
        sreg[2] = lcsr[dl * SLOTS + 32 + i];
        sreg[3] = lcsr[dl * SLOTS + 48 + i];
        sreg[4] = lcsr[dl * SLOTS + 64 + (i & 7)];
        float4 acc = {0.f, 0.f, 0.f, 0.f};
        float dsum = 0.f;
#pragma unroll
        for (int k = 0; k < 5; ++k) {
            if (dg > k * 16) {
                int cnt = dg - k * 16;
                int reg = sreg[k];
#pragma unroll
                for (int u0 = 0; u0 < 16; u0 += 8) {
                    int s8[8]; float g8[8]; float4 x8[8]; float w8[8];
#pragma unroll
                    for (int u = 0; u < 8; ++u) {
                        int raw = __shfl(reg, qsel | (u0 + u), 64);
                        s8[u] = (u0 + u < cnt) ? raw : 0;
                    }
#pragma unroll
                    for (int u = 0; u < 8; ++u) g8[u] = asrch[s8[u] * NH];
#pragma unroll
                    for (int u = 0; u < 8; ++u)
                        x8[u] = *(const float4*)(xpi + (size_t)s8[u] * HC);
#pragma unroll
                    for (int u = 0; u < 8; ++u) {
                        float e = g8[u] + adh;
                        e = fmaxf(e, 0.2f * e);
                        w8[u] = (u0 + u < cnt) ? __expf(e) : 0.f;
                    }
#pragma unroll
                    for (int u = 0; u < 8; ++u) {
                        dsum += w8[u];
                        acc.x = fmaf(w8[u], x8[u].x, acc.x);
                        acc.y = fmaf(w8[u], x8[u].y, acc.y);
                        acc.z = fmaf(w8[u], x8[u].z, acc.z);
                        acc.w = fmaf(w8[u], x8[u].w, acc.w);
                    }
                }
            }
        }
        if (dst < N_NODES) {
            float inv = 1.f / (dsum + 1e-16f);
            float4 o;
            o.x = acc.x * inv + bz.x;
            o.y = acc.y * inv + bz.y;
            o.z = acc.z * inv + bz.z;
            o.w = acc.w * inv + bz.w;
            *(float4*)(out + (size_t)dst * HC + 4 * i) = o;
        }
    }
}

// ---------------------------------------------------------------- launcher
extern "C" void kernel_launch(void* const* d_in, const int* in_sizes, int n_in,
                              void* d_out, int out_size, void* d_ws, size_t ws_size,
                              hipStream_t stream) {
    const float* x       = (const float*)d_in[0];
    const int*   ei      = (const int*)d_in[1];   // [2][E]
    const float* W       = (const float*)d_in[2];
    const float* att_src = (const float*)d_in[3];
    const float* att_dst = (const float*)d_in[4];
    const float* bias    = (const float*)d_in[5];
    float* out = (float*)d_out;

    char* ws = (char*)d_ws;
    float*        xp      = (float*)(ws);              // 12,800,000 B
    float*        a_srcv  = (float*)(ws + 12800000);   //    800,000 B
    float*        a_dstv  = (float*)(ws + 13600000);   //    800,000 B
    // gap [14.4M, 14.43M): absorbs guarded a_dst reads for dst in [50000,50048)
    int*          gcursor = (int*)  (ws + 14432768);   //      6,256 B (NB ints)
    unsigned int* barr    = (unsigned int*)(ws + 14449152); // 8,007,680 B (16-aligned)
    // total ~22.5 MB

    hipMemsetAsync(gcursor, 0, NB * sizeof(int), stream);
    gemm_attn_kernel<<<782, 256, 0, stream>>>(x, W, att_src, att_dst,
                                              xp, a_srcv, a_dstv);
    bucket_kernel<<<(N_EDGES / 16 + 255) / 256, 256, 0, stream>>>(ei, gcursor, barr);
    fused_gather_kernel<<<NB, 256, 0, stream>>>(barr, gcursor,
                                                a_srcv, a_dstv, xp, bias, out);
}

// Round 9
// 176.841 us; speedup vs baseline: 1.3861x; 1.3861x over previous
//
#include <hip/hip_runtime.h>
#include <math.h>

#define N_NODES 50000
#define N_EDGES 1600000
#define IN_DIM  128
#define HC      64   // H*C
#define NH      4    // heads
#define SLOTS   72   // padded CSR slots per node; true max degree ~55
#define NB      1564 // buckets: dst >> 5, 32 nodes each (1564*32 = 50048)
#define BCAP    1280 // per-bucket capacity: mean 1024 + 8 sigma

// ---------------------------------------------------------------- GEMM + logits
// v3: W in LDS [64][132] (pad 132: lane stride 132 ≡ 4 mod 32 -> all 16 lanes
// hit distinct bank groups, conflict-free b128). x read straight from global:
// all 16 lanes of a quarter issue the SAME address (4 lines/wave-instr).
// Thread = 4 nodes x 4 cols (i, i+16, i+32, i+48 -> one col per head):
// per 4k-step, 8 b128 loads feed 64 FMAs; 16 independent acc chains.
__global__ __launch_bounds__(256) void gemm_attn_kernel(
    const float* __restrict__ x, const float* __restrict__ W,
    const float* __restrict__ att_src, const float* __restrict__ att_dst,
    float* __restrict__ xp, float* __restrict__ a_src, float* __restrict__ a_dst) {
    __shared__ float Wl[64 * 132];
    int tid = (int)threadIdx.x;
    {   // stage W: 2048 float4, coalesced, 8 per thread
        const float4* W4 = (const float4*)W;
#pragma unroll
        for (int j = 0; j < 8; ++j) {
            int f = j * 256 + tid;
            int c = f >> 5, k4 = f & 31;
            *(float4*)&Wl[c * 132 + k4 * 4] = W4[f];   // 528B row: 16B aligned
        }
    }
    __syncthreads();

    int l = tid & 63, w = tid >> 6, q = l >> 4, i = l & 15;
    int n0 = blockIdx.x * 64 + w * 16 + q * 4;       // block: 64 nodes
    int nj[4];
#pragma unroll
    for (int j = 0; j < 4; ++j) {
        int n = n0 + j;
        nj[j] = (n < N_NODES) ? n : N_NODES - 1;     // clamp loads; stores guarded
    }

    const float* wlp = Wl + i * 132;                 // rows i, i+16, i+32, i+48
    float4 acc[4] = {{0,0,0,0},{0,0,0,0},{0,0,0,0},{0,0,0,0}};
    float4 xr[4], xn[4];
#pragma unroll
    for (int j = 0; j < 4; ++j) xr[j] = *(const float4*)(x + (size_t)nj[j] * IN_DIM);

#pragma unroll 2
    for (int k0 = 0; k0 < IN_DIM; k0 += 4) {
        if (k0 + 4 < IN_DIM) {
#pragma unroll
            for (int j = 0; j < 4; ++j)
                xn[j] = *(const float4*)(x + (size_t)nj[j] * IN_DIM + k0 + 4);
        }
        float4 wl0 = *(const float4*)(wlp + 0 * 16 * 132 + k0);
        float4 wl1 = *(const float4*)(wlp + 1 * 16 * 132 + k0);
        float4 wl2 = *(const float4*)(wlp + 2 * 16 * 132 + k0);
        float4 wl3 = *(const float4*)(wlp + 3 * 16 * 132 + k0);
#pragma unroll
        for (int j = 0; j < 4; ++j) {
            float4 xv = xr[j];
            acc[j].x = fmaf(xv.x, wl0.x, fmaf(xv.y, wl0.y, fmaf(xv.z, wl0.z, fmaf(xv.w, wl0.w, acc[j].x))));
            acc[j].y = fmaf(xv.x, wl1.x, fmaf(xv.y, wl1.y, fmaf(xv.z, wl1.z, fmaf(xv.w, wl1.w, acc[j].y))));
            acc[j].z = fmaf(xv.x, wl2.x, fmaf(xv.y, wl2.y, fmaf(xv.z, wl2.z, fmaf(xv.w, wl2.w, acc[j].z))));
            acc[j].w = fmaf(xv.x, wl3.x, fmaf(xv.y, wl3.y, fmaf(xv.z, wl3.z, fmaf(xv.w, wl3.w, acc[j].w))));
        }
#pragma unroll
        for (int j = 0; j < 4; ++j) xr[j] = xn[j];
    }

    // logits: lane i holds one col per head (i+16h). Butterfly over the 16-lane
    // quarter reduces all 4 heads simultaneously in .x/.y/.z/.w.
    float a_s0 = att_src[i], a_s1 = att_src[16 + i], a_s2 = att_src[32 + i], a_s3 = att_src[48 + i];
    float a_d0 = att_dst[i], a_d1 = att_dst[16 + i], a_d2 = att_dst[32 + i], a_d3 = att_dst[48 + i];
#pragma unroll
    for (int j = 0; j < 4; ++j) {
        int n = n0 + j;
        if (n < N_NODES) {                            // quarter-uniform guard
            xp[(size_t)n * HC + i]      = acc[j].x;   // 4x 64B coalesced stores
            xp[(size_t)n * HC + 16 + i] = acc[j].y;
            xp[(size_t)n * HC + 32 + i] = acc[j].z;
            xp[(size_t)n * HC + 48 + i] = acc[j].w;
            float4 ps, pd;
            ps.x = acc[j].x * a_s0; ps.y = acc[j].y * a_s1;
            ps.z = acc[j].z * a_s2; ps.w = acc[j].w * a_s3;
            pd.x = acc[j].x * a_d0; pd.y = acc[j].y * a_d1;
            pd.z = acc[j].z * a_d2; pd.w = acc[j].w * a_d3;
#pragma unroll
            for (int off = 1; off < 16; off <<= 1) {  // stays within quarter
                ps.x += __shfl_xor(ps.x, off, 64); ps.y += __shfl_xor(ps.y, off, 64);
                ps.z += __shfl_xor(ps.z, off, 64); ps.w += __shfl_xor(ps.w, off, 64);
                pd.x += __shfl_xor(pd.x, off, 64); pd.y += __shfl_xor(pd.y, off, 64);
                pd.z += __shfl_xor(pd.z, off, 64); pd.w += __shfl_xor(pd.w, off, 64);
            }
            if (i == 0) {
                *(float4*)(a_src + n * NH) = ps;      // heads 0..3
                *(float4*)(a_dst + n * NH) = pd;
            }
        }
    }
}

// ---------------------------------------------------------------- bucket pass
// Bin edges by dst>>5. 196 blocks x 512 threads, 16 edges/thread: gcursor
// atomics = 196*NB = 306k (half of R8), lbase rounds 3.05 (was 6.1).
__global__ __launch_bounds__(512) void bucket_kernel(
    const int* __restrict__ ei, int* __restrict__ gcursor,
    unsigned int* __restrict__ barr) {
    __shared__ int lcount[NB];
    __shared__ int lbase[NB];
    int tid = threadIdx.x;
    for (int j = tid; j < NB; j += 512) lcount[j] = 0;
    __syncthreads();
    int gid = blockIdx.x * 512 + tid;            // 16-edge group id (100000 total)
    bool active = gid < N_EDGES / 16;            // NO early return (barriers)
    int s[16], d[16], b[16], lpos[16];
    if (active) {
        const int4* sp = (const int4*)ei;
        const int4* dp = (const int4*)(ei + N_EDGES);
#pragma unroll
        for (int v = 0; v < 4; ++v) {
            int4 sv = sp[4 * gid + v];
            int4 dv = dp[4 * gid + v];
            s[4*v+0] = sv.x; s[4*v+1] = sv.y; s[4*v+2] = sv.z; s[4*v+3] = sv.w;
            d[4*v+0] = dv.x; d[4*v+1] = dv.y; d[4*v+2] = dv.z; d[4*v+3] = dv.w;
        }
#pragma unroll
        for (int u = 0; u < 16; ++u) {
            b[u] = d[u] >> 5;
            lpos[u] = atomicAdd(&lcount[b[u]], 1);
        }
    }
    __syncthreads();
    for (int j = tid; j < NB; j += 512) {
        int c = lcount[j];
        lbase[j] = (c > 0) ? atomicAdd(&gcursor[j], c) : 0;
    }
    __syncthreads();
    if (active) {
#pragma unroll
        for (int u = 0; u < 16; ++u) {
            int pos = lbase[b[u]] + lpos[u];
            if (pos < BCAP)   // statistically impossible overflow; never corrupt
                barr[(size_t)b[u] * BCAP + pos] =
                    (unsigned)s[u] | ((unsigned)(d[u] & 31) << 20);
        }
    }
}

// ---------------------------------------------------------------- fused CSR + gather
// One 256-thread block per 32-node bucket (NB=1564 -> 6.1 blocks/CU).
// Phase A: coalesced uint4 record reads -> LDS CSR (LDS atomics only).
// Phase B: 4 dst/wave, 16 lanes/dst, float4/lane; 2 rounds cover 32 nodes.
__global__ __launch_bounds__(256) void fused_gather_kernel(
    const unsigned int* __restrict__ barr, const int* __restrict__ gcursor,
    const float* __restrict__ a_src, const float* __restrict__ a_dst,
    const float* __restrict__ xp, const float* __restrict__ bias,
    float* __restrict__ out) {
    __shared__ int lcsr[32 * SLOTS];   // 9216 B
    __shared__ int deg[32];
    int b = blockIdx.x, tid = (int)threadIdx.x;
    if (tid < 32) deg[tid] = 0;
    __syncthreads();
    int n = gcursor[b];
    n = (n < BCAP) ? n : BCAP;
    const unsigned int* src = barr + (size_t)b * BCAP;

    // ---- phase A: build LDS adjacency (1280 records max = 2 rounds)
    for (int i0 = 0; i0 < n; i0 += 1024) {
        int ibase = i0 + tid * 4;
        unsigned v[4]; bool val[4]; int dp[4], pos[4];
        if (ibase < n) {
            uint4 r = *(const uint4*)(src + ibase);   // BCAP mult of 4, 16B aligned
            v[0] = r.x; v[1] = r.y; v[2] = r.z; v[3] = r.w;
        } else { v[0] = v[1] = v[2] = v[3] = 0u; }
#pragma unroll
        for (int u = 0; u < 4; ++u) {
            val[u] = (ibase + u) < n;
            dp[u] = (int)(v[u] >> 20);
            if (val[u]) pos[u] = atomicAdd(&deg[dp[u]], 1);
        }
#pragma unroll
        for (int u = 0; u < 4; ++u)
            if (val[u] && pos[u] < SLOTS)
                lcsr[dp[u] * SLOTS + pos[u]] = (int)(v[u] & 0xFFFFF);
    }
    __syncthreads();

    // ---- phase B: gather
    int l = tid & 63;
    int w = tid >> 6;                 // wave 0..3
    int q = l >> 4;                   // quarter
    int i = l & 15;                   // lane within quarter
    int h = i >> 2;                   // head of this lane's 4 channels
    const float* xpi = xp + 4 * i;
    const float* asrch = a_src + h;
    int qsel = l & 48;
    float4 bz = *(const float4*)(bias + 4 * i);

#pragma unroll
    for (int r = 0; r < 2; ++r) {
        int dl = w * 8 + r * 4 + q;           // local node 0..31
        int dst = (b << 5) + dl;
        int dg = deg[dl];
        dg = (dg < SLOTS) ? dg : SLOTS;
        // dst in [50000,50048): a_dst read lands in d_ws gap region (safe,
        // allocated); dg==0 there and the store is guarded.
        float adh = a_dst[dst * NH + h];
        int sreg[5];
        sreg[0] = lcsr[dl * SLOTS + i];
        sreg[1] = lcsr[dl * SLOTS + 16 + i];
        sreg[2] = lcsr[dl * SLOTS + 32 + i];
        sreg[3] = lcsr[dl * SLOTS + 48 + i];
        sreg[4] = lcsr[dl * SLOTS + 64 + (i & 7)];
        float4 acc = {0.f, 0.f, 0.f, 0.f};
        float dsum = 0.f;
#pragma unroll
        for (int k = 0; k < 5; ++k) {
            if (dg > k * 16) {
                int cnt = dg - k * 16;
                int reg = sreg[k];
#pragma unroll
                for (int u0 = 0; u0 < 16; u0 += 8) {
                    int s8[8]; float g8[8]; float4 x8[8]; float w8[8];
#pragma unroll
                    for (int u = 0; u < 8; ++u) {
                        int raw = __shfl(reg, qsel | (u0 + u), 64);
                        s8[u] = (u0 + u < cnt) ? raw : 0;
                    }
#pragma unroll
                    for (int u = 0; u < 8; ++u) g8[u] = asrch[s8[u] * NH];
#pragma unroll
                    for (int u = 0; u < 8; ++u)
                        x8[u] = *(const float4*)(xpi + (size_t)s8[u] * HC);
#pragma unroll
                    for (int u = 0; u < 8; ++u) {
                        float e = g8[u] + adh;
                        e = fmaxf(e, 0.2f * e);
                        w8[u] = (u0 + u < cnt) ? __expf(e) : 0.f;
                    }
#pragma unroll
                    for (int u = 0; u < 8; ++u) {
                        dsum += w8[u];
                        acc.x = fmaf(w8[u], x8[u].x, acc.x);
                        acc.y = fmaf(w8[u], x8[u].y, acc.y);
                        acc.z = fmaf(w8[u], x8[u].z, acc.z);
                        acc.w = fmaf(w8[u], x8[u].w, acc.w);
                    }
                }
            }
        }
        if (dst < N_NODES) {
            float inv = 1.f / (dsum + 1e-16f);
            float4 o;
            o.x = acc.x * inv + bz.x;
            o.y = acc.y * inv + bz.y;
            o.z = acc.z * inv + bz.z;
            o.w = acc.w * inv + bz.w;
            *(float4*)(out + (size_t)dst * HC + 4 * i) = o;
        }
    }
}

// ---------------------------------------------------------------- launcher
extern "C" void kernel_launch(void* const* d_in, const int* in_sizes, int n_in,
                              void* d_out, int out_size, void* d_ws, size_t ws_size,
                              hipStream_t stream) {
    const float* x       = (const float*)d_in[0];
    const int*   ei      = (const int*)d_in[1];   // [2][E]
    const float* W       = (const float*)d_in[2];
    const float* att_src = (const float*)d_in[3];
    const float* att_dst = (const float*)d_in[4];
    const float* bias    = (const float*)d_in[5];
    float* out = (float*)d_out;

    char* ws = (char*)d_ws;
    float*        xp      = (float*)(ws);              // 12,800,000 B
    float*        a_srcv  = (float*)(ws + 12800000);   //    800,000 B
    float*        a_dstv  = (float*)(ws + 13600000);   //    800,000 B
    // gap [14.4M, 14.43M): absorbs guarded a_dst reads for dst in [50000,50048)
    int*          gcursor = (int*)  (ws + 14432768);   //      6,256 B (NB ints)
    unsigned int* barr    = (unsigned int*)(ws + 14449152); // 8,007,680 B (16-aligned)
    // total ~22.5 MB

    hipMemsetAsync(gcursor, 0, NB * sizeof(int), stream);
    gemm_attn_kernel<<<782, 256, 0, stream>>>(x, W, att_src, att_dst,
                                              xp, a_srcv, a_dstv);
    bucket_kernel<<<196, 512, 0, stream>>>(ei, gcursor, barr);
    fused_gather_kernel<<<NB, 256, 0, stream>>>(barr, gcursor,
                                                a_srcv, a_dstv, xp, bias, out);
}

// Round 10
// 153.212 us; speedup vs baseline: 1.5999x; 1.1542x over previous
//
#include <hip/hip_runtime.h>
#include <hip/hip_bf16.h>
#include <math.h>

#define N_NODES 50000
#define N_EDGES 1600000
#define IN_DIM  128
#define HC      64   // H*C
#define NH      4    // heads
#define SLOTS   72   // padded CSR slots per node; true max degree ~58
#define NB      1564 // buckets: dst >> 5, 32 nodes each (1564*32 = 50048)
#define BCAP    1280 // per-bucket capacity: mean 1024 + 8 sigma
#define GEMM_BLOCKS 391   // 391*128 = 50048 nodes
#define FAT_LDS 33792     // max(gemm 64*132*4, bucket 2*NB*4)

// ---------------------------------------------------------------- fat kernel
// Blocks [0,391): GEMM+logits (VALU/LDS-bound). Blocks [391,587): edge
// bucketing (atomic/latency-bound). Independent work; co-resident waves
// overlap the two pipes (m114) and one launch gap disappears.
__global__ __launch_bounds__(512) void gemm_bucket_kernel(
    const float* __restrict__ x, const float* __restrict__ W,
    const float* __restrict__ att_src, const float* __restrict__ att_dst,
    const int* __restrict__ ei,
    __hip_bfloat16* __restrict__ xp, float* __restrict__ a_src,
    float* __restrict__ a_dst,
    int* __restrict__ gcursor, unsigned int* __restrict__ barr) {
    extern __shared__ char smraw[];
    int tid = (int)threadIdx.x;

    if (blockIdx.x < GEMM_BLOCKS) {
        // ---- GEMM v3 (R9 structure, 512 threads = 128 nodes/block), bf16 xp out.
        // W in LDS [64][132] (pad 132: stride ≡ 4 mod 32 -> conflict-free b128).
        // x read from global: 16 lanes of a quarter issue the SAME address.
        float* Wl = (float*)smraw;
        const float4* W4 = (const float4*)W;
#pragma unroll
        for (int j = 0; j < 4; ++j) {            // 2048 float4 / 512 threads
            int f = j * 512 + tid;
            int c = f >> 5, k4 = f & 31;
            *(float4*)&Wl[c * 132 + k4 * 4] = W4[f];
        }
        __syncthreads();

        int l = tid & 63, w = tid >> 6, q = l >> 4, i = l & 15;
        int n0 = blockIdx.x * 128 + w * 16 + q * 4;
        int nj[4];
#pragma unroll
        for (int j = 0; j < 4; ++j) {
            int n = n0 + j;
            nj[j] = (n < N_NODES) ? n : N_NODES - 1;   // clamp loads; stores guarded
        }
        const float* wlp = Wl + i * 132;               // rows i,i+16,i+32,i+48
        float4 acc[4] = {{0,0,0,0},{0,0,0,0},{0,0,0,0},{0,0,0,0}};
        float4 xr[4], xn[4];
#pragma unroll
        for (int j = 0; j < 4; ++j) xr[j] = *(const float4*)(x + (size_t)nj[j] * IN_DIM);
#pragma unroll 2
        for (int k0 = 0; k0 < IN_DIM; k0 += 4) {
            if (k0 + 4 < IN_DIM) {
#pragma unroll
                for (int j = 0; j < 4; ++j)
                    xn[j] = *(const float4*)(x + (size_t)nj[j] * IN_DIM + k0 + 4);
            }
            float4 wl0 = *(const float4*)(wlp + 0 * 16 * 132 + k0);
            float4 wl1 = *(const float4*)(wlp + 1 * 16 * 132 + k0);
            float4 wl2 = *(const float4*)(wlp + 2 * 16 * 132 + k0);
            float4 wl3 = *(const float4*)(wlp + 3 * 16 * 132 + k0);
#pragma unroll
            for (int j = 0; j < 4; ++j) {
                float4 xv = xr[j];
                acc[j].x = fmaf(xv.x, wl0.x, fmaf(xv.y, wl0.y, fmaf(xv.z, wl0.z, fmaf(xv.w, wl0.w, acc[j].x))));
                acc[j].y = fmaf(xv.x, wl1.x, fmaf(xv.y, wl1.y, fmaf(xv.z, wl1.z, fmaf(xv.w, wl1.w, acc[j].y))));
                acc[j].z = fmaf(xv.x, wl2.x, fmaf(xv.y, wl2.y, fmaf(xv.z, wl2.z, fmaf(xv.w, wl2.w, acc[j].z))));
                acc[j].w = fmaf(xv.x, wl3.x, fmaf(xv.y, wl3.y, fmaf(xv.z, wl3.z, fmaf(xv.w, wl3.w, acc[j].w))));
            }
#pragma unroll
            for (int j = 0; j < 4; ++j) xr[j] = xn[j];
        }

        float a_s0 = att_src[i], a_s1 = att_src[16 + i], a_s2 = att_src[32 + i], a_s3 = att_src[48 + i];
        float a_d0 = att_dst[i], a_d1 = att_dst[16 + i], a_d2 = att_dst[32 + i], a_d3 = att_dst[48 + i];
#pragma unroll
        for (int j = 0; j < 4; ++j) {
            int n = n0 + j;
            if (n < N_NODES) {                          // quarter-uniform guard
                __hip_bfloat16* xw = xp + (size_t)n * HC;
                xw[i]      = __float2bfloat16(acc[j].x);   // 32B/quarter stores
                xw[16 + i] = __float2bfloat16(acc[j].y);
                xw[32 + i] = __float2bfloat16(acc[j].z);
                xw[48 + i] = __float2bfloat16(acc[j].w);
                float4 ps, pd;
                ps.x = acc[j].x * a_s0; ps.y = acc[j].y * a_s1;
                ps.z = acc[j].z * a_s2; ps.w = acc[j].w * a_s3;
                pd.x = acc[j].x * a_d0; pd.y = acc[j].y * a_d1;
                pd.z = acc[j].z * a_d2; pd.w = acc[j].w * a_d3;
#pragma unroll
                for (int off = 1; off < 16; off <<= 1) {  // stays within quarter
                    ps.x += __shfl_xor(ps.x, off, 64); ps.y += __shfl_xor(ps.y, off, 64);
                    ps.z += __shfl_xor(ps.z, off, 64); ps.w += __shfl_xor(ps.w, off, 64);
                    pd.x += __shfl_xor(pd.x, off, 64); pd.y += __shfl_xor(pd.y, off, 64);
                    pd.z += __shfl_xor(pd.z, off, 64); pd.w += __shfl_xor(pd.w, off, 64);
                }
                if (i == 0) {
                    *(float4*)(a_src + n * NH) = ps;
                    *(float4*)(a_dst + n * NH) = pd;
                }
            }
        }
    } else {
        // ---- bucket pass (R9 body). Bin edges by dst>>5; LDS-atomic local
        // positions + one global atomic per bucket per block; packed appends.
        int* lcount = (int*)smraw;
        int* lbase  = lcount + NB;
        for (int j = tid; j < NB; j += 512) lcount[j] = 0;
        __syncthreads();
        int gid = (blockIdx.x - GEMM_BLOCKS) * 512 + tid;   // 16-edge group id
        bool active = gid < N_EDGES / 16;                   // NO early return
        int s[16], d[16], b[16], lpos[16];
        if (active) {
            const int4* sp = (const int4*)ei;
            const int4* dp = (const int4*)(ei + N_EDGES);
#pragma unroll
            for (int v = 0; v < 4; ++v) {
                int4 sv = sp[4 * gid + v];
                int4 dv = dp[4 * gid + v];
                s[4*v+0] = sv.x; s[4*v+1] = sv.y; s[4*v+2] = sv.z; s[4*v+3] = sv.w;
                d[4*v+0] = dv.x; d[4*v+1] = dv.y; d[4*v+2] = dv.z; d[4*v+3] = dv.w;
            }
#pragma unroll
            for (int u = 0; u < 16; ++u) {
                b[u] = d[u] >> 5;
                lpos[u] = atomicAdd(&lcount[b[u]], 1);
            }
        }
        __syncthreads();
        for (int j = tid; j < NB; j += 512) {
            int c = lcount[j];
            lbase[j] = (c > 0) ? atomicAdd(&gcursor[j], c) : 0;
        }
        __syncthreads();
        if (active) {
#pragma unroll
            for (int u = 0; u < 16; ++u) {
                int pos = lbase[b[u]] + lpos[u];
                if (pos < BCAP)   // statistically impossible; never corrupt
                    barr[(size_t)b[u] * BCAP + pos] =
                        (unsigned)s[u] | ((unsigned)(d[u] & 31) << 20);
            }
        }
    }
}

// ---------------------------------------------------------------- fused CSR + gather
// One 256-thread block per 32-node bucket. Phase A: coalesced uint4 record
// reads -> LDS CSR (LDS atomics only). Phase B: 4 dst/wave, 16 lanes/dst,
// 4 channels/lane; xp gathered as bf16 (uint2 = 8B/lane -> 128B row, and
// xp shrinks to 6.4MB for better per-XCD L2 residency), unpacked via shifts.
__global__ __launch_bounds__(256) void fused_gather_kernel(
    const unsigned int* __restrict__ barr, const int* __restrict__ gcursor,
    const float* __restrict__ a_src, const float* __restrict__ a_dst,
    const __hip_bfloat16* __restrict__ xp, const float* __restrict__ bias,
    float* __restrict__ out) {
    __shared__ int lcsr[32 * SLOTS];   // 9216 B
    __shared__ int deg[32];
    int b = blockIdx.x, tid = (int)threadIdx.x;
    if (tid < 32) deg[tid] = 0;
    __syncthreads();
    int n = gcursor[b];
    n = (n < BCAP) ? n : BCAP;
    const unsigned int* src = barr + (size_t)b * BCAP;

    // ---- phase A: build LDS adjacency (<=1280 records = 2 rounds)
    for (int i0 = 0; i0 < n; i0 += 1024) {
        int ibase = i0 + tid * 4;
        unsigned v[4]; bool val[4]; int dp[4], pos[4];
        if (ibase < n) {
            uint4 r = *(const uint4*)(src + ibase);   // BCAP mult of 4, 16B aligned
            v[0] = r.x; v[1] = r.y; v[2] = r.z; v[3] = r.w;
        } else { v[0] = v[1] = v[2] = v[3] = 0u; }
#pragma unroll
        for (int u = 0; u < 4; ++u) {
            val[u] = (ibase + u) < n;
            dp[u] = (int)(v[u] >> 20);
            if (val[u]) pos[u] = atomicAdd(&deg[dp[u]], 1);
        }
#pragma unroll
        for (int u = 0; u < 4; ++u)
            if (val[u] && pos[u] < SLOTS)
                lcsr[dp[u] * SLOTS + pos[u]] = (int)(v[u] & 0xFFFFF);
    }
    __syncthreads();

    // ---- phase B: gather
    int l = tid & 63;
    int w = tid >> 6;                 // wave 0..3
    int q = l >> 4;                   // quarter
    int i = l & 15;                   // lane within quarter
    int h = i >> 2;                   // head of this lane's 4 channels
    const unsigned short* xpi = (const unsigned short*)xp + 4 * i;
    const float* asrch = a_src + h;
    int qsel = l & 48;
    float4 bz = *(const float4*)(bias + 4 * i);

#pragma unroll
    for (int r = 0; r < 2; ++r) {
        int dl = w * 8 + r * 4 + q;           // local node 0..31
        int dst = (b << 5) + dl;
        int dg = deg[dl];
        dg = (dg < SLOTS) ? dg : SLOTS;
        // dst in [50000,50048): a_dst read lands inside ws (pad region); value
        // unused (dg==0) and the store is guarded.
        float adh = a_dst[dst * NH + h];
        int sreg[5];
        sreg[0] = lcsr[dl * SLOTS + i];
        sreg[1] = lcsr[dl * SLOTS + 16 + i];
        sreg[2] = lcsr[dl * SLOTS + 32 + i];
        sreg[3] = lcsr[dl * SLOTS + 48 + i];
        sreg[4] = lcsr[dl * SLOTS + 64 + (i & 7)];
        float4 acc = {0.f, 0.f, 0.f, 0.f};
        float dsum = 0.f;
#pragma unroll
        for (int k = 0; k < 5; ++k) {
            if (dg > k * 16) {
                int cnt = dg - k * 16;
                int reg = sreg[k];
#pragma unroll
                for (int u0 = 0; u0 < 16; u0 += 8) {
                    int s8[8]; float g8[8]; uint2 t8[8]; float w8[8];
#pragma unroll
                    for (int u = 0; u < 8; ++u) {
                        int raw = __shfl(reg, qsel | (u0 + u), 64);
                        s8[u] = (u0 + u < cnt) ? raw : 0;
                    }
#pragma unroll
                    for (int u = 0; u < 8; ++u) g8[u] = asrch[s8[u] * NH];
#pragma unroll
                    for (int u = 0; u < 8; ++u)
                        t8[u] = *(const uint2*)(xpi + (size_t)s8[u] * HC);
#pragma unroll
                    for (int u = 0; u < 8; ++u) {
                        float e = g8[u] + adh;
                        e = fmaxf(e, 0.2f * e);
                        w8[u] = (u0 + u < cnt) ? __expf(e) : 0.f;
                    }
#pragma unroll
                    for (int u = 0; u < 8; ++u) {
                        float x0 = __uint_as_float(t8[u].x << 16);
                        float x1 = __uint_as_float(t8[u].x & 0xffff0000u);
                        float x2 = __uint_as_float(t8[u].y << 16);
                        float x3 = __uint_as_float(t8[u].y & 0xffff0000u);
                        dsum += w8[u];
                        acc.x = fmaf(w8[u], x0, acc.x);
                        acc.y = fmaf(w8[u], x1, acc.y);
                        acc.z = fmaf(w8[u], x2, acc.z);
                        acc.w = fmaf(w8[u], x3, acc.w);
                    }
                }
            }
        }
        if (dst < N_NODES) {
            float inv = 1.f / (dsum + 1e-16f);
            float4 o;
            o.x = acc.x * inv + bz.x;
            o.y = acc.y * inv + bz.y;
            o.z = acc.z * inv + bz.z;
            o.w = acc.w * inv + bz.w;
            *(float4*)(out + (size_t)dst * HC + 4 * i) = o;
        }
    }
}

// ---------------------------------------------------------------- launcher
extern "C" void kernel_launch(void* const* d_in, const int* in_sizes, int n_in,
                              void* d_out, int out_size, void* d_ws, size_t ws_size,
                              hipStream_t stream) {
    const float* x       = (const float*)d_in[0];
    const int*   ei      = (const int*)d_in[1];   // [2][E]
    const float* W       = (const float*)d_in[2];
    const float* att_src = (const float*)d_in[3];
    const float* att_dst = (const float*)d_in[4];
    const float* bias    = (const float*)d_in[5];
    float* out = (float*)d_out;

    char* ws = (char*)d_ws;
    __hip_bfloat16* xp      = (__hip_bfloat16*)(ws);   //  6,400,000 B
    float*          a_srcv  = (float*)(ws + 6400000);  //    800,000 B
    float*          a_dstv  = (float*)(ws + 7200000);  //    800,000 B
    // pad [8.0M, 8.016M): absorbs guarded a_dst reads for dst in [50000,50048)
    int*            gcursor = (int*)  (ws + 8016384);  //      6,256 B (NB ints)
    unsigned int*   barr    = (unsigned int*)(ws + 8032768); // 8,007,680 B
    // total ~16.0 MB

    hipMemsetAsync(gcursor, 0, NB * sizeof(int), stream);
    gemm_bucket_kernel<<<GEMM_BLOCKS + 196, 512, FAT_LDS, stream>>>(
        x, W, att_src, att_dst, ei, xp, a_srcv, a_dstv, gcursor, barr);
    fused_gather_kernel<<<NB, 256, 0, stream>>>(barr, gcursor,
                                                a_srcv, a_dstv, xp, bias, out);
}

// Round 11
// 145.834 us; speedup vs baseline: 1.6808x; 1.0506x over previous
//
#include <hip/hip_runtime.h>
#include <hip/hip_bf16.h>
#include <math.h>

#define N_NODES 50000
#define N_EDGES 1600000
#define IN_DIM  128
#define HC      64   // H*C
#define NH      4    // heads
#define SLOTS   72   // padded CSR slots per node; true max degree ~58
#define NB      1564 // buckets: dst >> 5, 32 nodes each (1564*32 = 50048)
#define BCAP    1280 // per-bucket capacity: mean 1024 + 8 sigma
#define GEMM_BLOCKS 391   // 391*128 = 50048 nodes
#define FAT_GRID 587      // 391 gemm + 196 bucket, INTERLEAVED (blockIdx%3==1 -> bucket)
#define FAT_LDS 33792     // max(gemm 64*132*4, bucket 2*NB*4)

// ---------------------------------------------------------------- fat kernel
// Roles interleaved so gemm (VALU/LDS-bound) and bucket (atomic/latency-bound)
// blocks are CO-RESIDENT from dispatch 0 (m114 overlap). R10 had bucket blocks
// at the grid tail -> serialized after gemm.
__global__ __launch_bounds__(512) void gemm_bucket_kernel(
    const float* __restrict__ x, const float* __restrict__ W,
    const float* __restrict__ att_src, const float* __restrict__ att_dst,
    const int* __restrict__ ei,
    __hip_bfloat16* __restrict__ xp, float* __restrict__ a_src,
    float* __restrict__ a_dst,
    int* __restrict__ gcursor, unsigned int* __restrict__ barr) {
    extern __shared__ char smraw[];
    int tid = (int)threadIdx.x;
    int bx  = (int)blockIdx.x;
    bool is_bucket = (bx % 3) == 1;          // 1,4,...,586: exactly 196 blocks

    if (!is_bucket) {
        // ---- GEMM+logits (R10 body). gemm block index among non-bucket blocks.
        int gb = bx - (bx + 1) / 3;          // 0..390
        float* Wl = (float*)smraw;
        const float4* W4 = (const float4*)W;
#pragma unroll
        for (int j = 0; j < 4; ++j) {        // 2048 float4 / 512 threads
            int f = j * 512 + tid;
            int c = f >> 5, k4 = f & 31;
            *(float4*)&Wl[c * 132 + k4 * 4] = W4[f];
        }
        __syncthreads();

        int l = tid & 63, w = tid >> 6, q = l >> 4, i = l & 15;
        int n0 = gb * 128 + w * 16 + q * 4;
        int nj[4];
#pragma unroll
        for (int j = 0; j < 4; ++j) {
            int n = n0 + j;
            nj[j] = (n < N_NODES) ? n : N_NODES - 1;   // clamp loads; stores guarded
        }
        const float* wlp = Wl + i * 132;               // rows i,i+16,i+32,i+48
        float4 acc[4] = {{0,0,0,0},{0,0,0,0},{0,0,0,0},{0,0,0,0}};
        float4 xr[4], xn[4];
#pragma unroll
        for (int j = 0; j < 4; ++j) xr[j] = *(const float4*)(x + (size_t)nj[j] * IN_DIM);
#pragma unroll 2
        for (int k0 = 0; k0 < IN_DIM; k0 += 4) {
            if (k0 + 4 < IN_DIM) {
#pragma unroll
                for (int j = 0; j < 4; ++j)
                    xn[j] = *(const float4*)(x + (size_t)nj[j] * IN_DIM + k0 + 4);
            }
            float4 wl0 = *(const float4*)(wlp + 0 * 16 * 132 + k0);
            float4 wl1 = *(const float4*)(wlp + 1 * 16 * 132 + k0);
            float4 wl2 = *(const float4*)(wlp + 2 * 16 * 132 + k0);
            float4 wl3 = *(const float4*)(wlp + 3 * 16 * 132 + k0);
#pragma unroll
            for (int j = 0; j < 4; ++j) {
                float4 xv = xr[j];
                acc[j].x = fmaf(xv.x, wl0.x, fmaf(xv.y, wl0.y, fmaf(xv.z, wl0.z, fmaf(xv.w, wl0.w, acc[j].x))));
                acc[j].y = fmaf(xv.x, wl1.x, fmaf(xv.y, wl1.y, fmaf(xv.z, wl1.z, fmaf(xv.w, wl1.w, acc[j].y))));
                acc[j].z = fmaf(xv.x, wl2.x, fmaf(xv.y, wl2.y, fmaf(xv.z, wl2.z, fmaf(xv.w, wl2.w, acc[j].z))));
                acc[j].w = fmaf(xv.x, wl3.x, fmaf(xv.y, wl3.y, fmaf(xv.z, wl3.z, fmaf(xv.w, wl3.w, acc[j].w))));
            }
#pragma unroll
            for (int j = 0; j < 4; ++j) xr[j] = xn[j];
        }

        float a_s0 = att_src[i], a_s1 = att_src[16 + i], a_s2 = att_src[32 + i], a_s3 = att_src[48 + i];
        float a_d0 = att_dst[i], a_d1 = att_dst[16 + i], a_d2 = att_dst[32 + i], a_d3 = att_dst[48 + i];
#pragma unroll
        for (int j = 0; j < 4; ++j) {
            int n = n0 + j;
            if (n < N_NODES) {                          // quarter-uniform guard
                __hip_bfloat16* xw = xp + (size_t)n * HC;
                xw[i]      = __float2bfloat16(acc[j].x);
                xw[16 + i] = __float2bfloat16(acc[j].y);
                xw[32 + i] = __float2bfloat16(acc[j].z);
                xw[48 + i] = __float2bfloat16(acc[j].w);
                float4 ps, pd;
                ps.x = acc[j].x * a_s0; ps.y = acc[j].y * a_s1;
                ps.z = acc[j].z * a_s2; ps.w = acc[j].w * a_s3;
                pd.x = acc[j].x * a_d0; pd.y = acc[j].y * a_d1;
                pd.z = acc[j].z * a_d2; pd.w = acc[j].w * a_d3;
#pragma unroll
                for (int off = 1; off < 16; off <<= 1) {  // stays within quarter
                    ps.x += __shfl_xor(ps.x, off, 64); ps.y += __shfl_xor(ps.y, off, 64);
                    ps.z += __shfl_xor(ps.z, off, 64); ps.w += __shfl_xor(ps.w, off, 64);
                    pd.x += __shfl_xor(pd.x, off, 64); pd.y += __shfl_xor(pd.y, off, 64);
                    pd.z += __shfl_xor(pd.z, off, 64); pd.w += __shfl_xor(pd.w, off, 64);
                }
                if (i == 0) {
                    *(float4*)(a_src + n * NH) = ps;
                    *(float4*)(a_dst + n * NH) = pd;
                }
            }
        }
    } else {
        // ---- bucket pass (R10 body). Bin edges by dst>>5; LDS-atomic local
        // positions + one global atomic per bucket per block; packed appends.
        int bb = (bx - 1) / 3;                          // 0..195
        int* lcount = (int*)smraw;
        int* lbase  = lcount + NB;
        for (int j = tid; j < NB; j += 512) lcount[j] = 0;
        __syncthreads();
        int gid = bb * 512 + tid;                       // 16-edge group id
        bool active = gid < N_EDGES / 16;               // NO early return
        int s[16], d[16], b[16], lpos[16];
        if (active) {
            const int4* sp = (const int4*)ei;
            const int4* dp = (const int4*)(ei + N_EDGES);
#pragma unroll
            for (int v = 0; v < 4; ++v) {
                int4 sv = sp[4 * gid + v];
                int4 dv = dp[4 * gid + v];
                s[4*v+0] = sv.x; s[4*v+1] = sv.y; s[4*v+2] = sv.z; s[4*v+3] = sv.w;
                d[4*v+0] = dv.x; d[4*v+1] = dv.y; d[4*v+2] = dv.z; d[4*v+3] = dv.w;
            }
#pragma unroll
            for (int u = 0; u < 16; ++u) {
                b[u] = d[u] >> 5;
                lpos[u] = atomicAdd(&lcount[b[u]], 1);
            }
        }
        __syncthreads();
        for (int j = tid; j < NB; j += 512) {
            int c = lcount[j];
            lbase[j] = (c > 0) ? atomicAdd(&gcursor[j], c) : 0;
        }
        __syncthreads();
        if (active) {
#pragma unroll
            for (int u = 0; u < 16; ++u) {
                int pos = lbase[b[u]] + lpos[u];
                if (pos < BCAP)   // statistically impossible; never corrupt
                    barr[(size_t)b[u] * BCAP + pos] =
                        (unsigned)s[u] | ((unsigned)(d[u] & 31) << 20);
            }
        }
    }
}

// ---------------------------------------------------------------- fused CSR + gather
// Layout B: 8 dst per wave, 8 lanes/dst, 8 channels/lane (uint4 = 8 bf16).
// Halves phase-B wave-instructions per edge vs R10 and doubles in-flight
// bytes per wave; phase B covers all 32 bucket nodes in ONE round.
__global__ __launch_bounds__(256) void fused_gather_kernel(
    const unsigned int* __restrict__ barr, const int* __restrict__ gcursor,
    const float* __restrict__ a_src, const float* __restrict__ a_dst,
    const __hip_bfloat16* __restrict__ xp, const float* __restrict__ bias,
    float* __restrict__ out) {
    __shared__ int lcsr[32 * SLOTS];   // 9216 B
    __shared__ int deg[32];
    int b = blockIdx.x, tid = (int)threadIdx.x;
    if (tid < 32) deg[tid] = 0;
    __syncthreads();
    int n = gcursor[b];
    n = (n < BCAP) ? n : BCAP;
    const unsigned int* src = barr + (size_t)b * BCAP;

    // ---- phase A: build LDS adjacency (<=1280 records = 2 rounds)
    for (int i0 = 0; i0 < n; i0 += 1024) {
        int ibase = i0 + tid * 4;
        unsigned v[4]; bool val[4]; int dp[4], pos[4];
        if (ibase < n) {
            uint4 r = *(const uint4*)(src + ibase);   // BCAP mult of 4, 16B aligned
            v[0] = r.x; v[1] = r.y; v[2] = r.z; v[3] = r.w;
        } else { v[0] = v[1] = v[2] = v[3] = 0u; }
#pragma unroll
        for (int u = 0; u < 4; ++u) {
            val[u] = (ibase + u) < n;
            dp[u] = (int)(v[u] >> 20);
            if (val[u]) pos[u] = atomicAdd(&deg[dp[u]], 1);
        }
#pragma unroll
        for (int u = 0; u < 4; ++u)
            if (val[u] && pos[u] < SLOTS)
                lcsr[dp[u] * SLOTS + pos[u]] = (int)(v[u] & 0xFFFFF);
    }
    __syncthreads();

    // ---- phase B: one round, 8 dst/wave
    int l = tid & 63;
    int w = tid >> 6;                 // wave 0..3
    int g = l >> 3;                   // group 0..7 (8 lanes each)
    int i = l & 7;                    // lane within group
    int h = i >> 1;                   // head of this lane's 8 channels
    int dl = w * 8 + g;               // local node 0..31
    int dst = (b << 5) + dl;
    int dg = deg[dl];
    dg = (dg < SLOTS) ? dg : SLOTS;
    // dst in [50000,50048): a_dst read lands inside ws (pad region); value
    // unused (dg==0) and the store is guarded.
    float adh = a_dst[dst * NH + h];

    int sreg[9];
#pragma unroll
    for (int k = 0; k < 9; ++k) sreg[k] = lcsr[dl * SLOTS + k * 8 + i];

    const unsigned short* xpi = (const unsigned short*)xp + 8 * i;  // lane's 8 ch
    const float* asrch = a_src + h;
    int gsel = l & 56;                // group base lane for shfl
    float a0=0,a1=0,a2=0,a3=0,a4=0,a5=0,a6=0,a7=0;
    float dsum = 0.f;

#pragma unroll
    for (int k = 0; k < 9; ++k) {
        if (dg > k * 8) {             // group-uniform; exec-mask guard
            int cnt = dg - k * 8;
            int reg = sreg[k];
            int s8[8]; float g8[8]; uint4 t8[8];
#pragma unroll
            for (int u = 0; u < 8; ++u) {
                int raw = __shfl(reg, gsel | u, 64);
                s8[u] = (u < cnt) ? raw : 0;          // safe dummy idx
            }
#pragma unroll
            for (int u = 0; u < 8; ++u) g8[u] = asrch[s8[u] * NH];
#pragma unroll
            for (int u = 0; u < 8; ++u)
                t8[u] = *(const uint4*)(xpi + (size_t)s8[u] * HC);
#pragma unroll
            for (int u = 0; u < 8; ++u) {
                float e = g8[u] + adh;
                e = fmaxf(e, 0.2f * e);
                float wv = (u < cnt) ? __expf(e) : 0.f;
                dsum += wv;
                uint4 t = t8[u];
                a0 = fmaf(wv, __uint_as_float(t.x << 16),          a0);
                a1 = fmaf(wv, __uint_as_float(t.x & 0xffff0000u),  a1);
                a2 = fmaf(wv, __uint_as_float(t.y << 16),          a2);
                a3 = fmaf(wv, __uint_as_float(t.y & 0xffff0000u),  a3);
                a4 = fmaf(wv, __uint_as_float(t.z << 16),          a4);
                a5 = fmaf(wv, __uint_as_float(t.z & 0xffff0000u),  a5);
                a6 = fmaf(wv, __uint_as_float(t.w << 16),          a6);
                a7 = fmaf(wv, __uint_as_float(t.w & 0xffff0000u),  a7);
            }
        }
    }
    if (dst < N_NODES) {
        float inv = 1.f / (dsum + 1e-16f);
        float4 b0 = *(const float4*)(bias + 8 * i);
        float4 b1 = *(const float4*)(bias + 8 * i + 4);
        float4 o0, o1;
        o0.x = a0 * inv + b0.x; o0.y = a1 * inv + b0.y;
        o0.z = a2 * inv + b0.z; o0.w = a3 * inv + b0.w;
        o1.x = a4 * inv + b1.x; o1.y = a5 * inv + b1.y;
        o1.z = a6 * inv + b1.z; o1.w = a7 * inv + b1.w;
        float* op = out + (size_t)dst * HC + 8 * i;
        *(float4*)op = o0;
        *(float4*)(op + 4) = o1;
    }
}

// ---------------------------------------------------------------- launcher
extern "C" void kernel_launch(void* const* d_in, const int* in_sizes, int n_in,
                              void* d_out, int out_size, void* d_ws, size_t ws_size,
                              hipStream_t stream) {
    const float* x       = (const float*)d_in[0];
    const int*   ei      = (const int*)d_in[1];   // [2][E]
    const float* W       = (const float*)d_in[2];
    const float* att_src = (const float*)d_in[3];
    const float* att_dst = (const float*)d_in[4];
    const float* bias    = (const float*)d_in[5];
    float* out = (float*)d_out;

    char* ws = (char*)d_ws;
    __hip_bfloat16* xp      = (__hip_bfloat16*)(ws);   //  6,400,000 B
    float*          a_srcv  = (float*)(ws + 6400000);  //    800,000 B
    float*          a_dstv  = (float*)(ws + 7200000);  //    800,000 B
    // pad [8.0M, 8.016M): absorbs guarded a_dst reads for dst in [50000,50048)
    int*            gcursor = (int*)  (ws + 8016384);  //      6,256 B (NB ints)
    unsigned int*   barr    = (unsigned int*)(ws + 8032768); // 8,007,680 B
    // total ~16.0 MB

    hipMemsetAsync(gcursor, 0, NB * sizeof(int), stream);
    gemm_bucket_kernel<<<FAT_GRID, 512, FAT_LDS, stream>>>(
        x, W, att_src, att_dst, ei, xp, a_srcv, a_dstv, gcursor, barr);
    fused_gather_kernel<<<NB, 256, 0, stream>>>(barr, gcursor,
                                                a_srcv, a_dstv, xp, bias, out);
}